// Round 9
// baseline (2979.926 us; speedup 1.0000x reference)
//
#include <hip/hip_runtime.h>

typedef float f32;
typedef unsigned int u32;
typedef unsigned short u16;
typedef short s16x8 __attribute__((ext_vector_type(8)));
typedef float f32x4 __attribute__((ext_vector_type(4)));
typedef u32 u32x4 __attribute__((ext_vector_type(4)));

#define S1F (-1.4426950408889634f)   /* -log2(e): r,z pre-scale */
#define S2F ( 2.8853900817779268f)   /* 2*log2(e): n pre-scale  */

__device__ __forceinline__ u16 f2bf(float x){
  u32 u = __float_as_uint(x);
  u32 r = u + 0x7FFFu + ((u >> 16) & 1u);   // round-to-nearest-even
  return (u16)(r >> 16);
}
#define B2F(v) __uint_as_float(((u32)(v)) << 16)

// async global->LDS 16B/lane (dest = wave-uniform base + lane*16)
__device__ __forceinline__ void gld16(const u16* g, u16* l){
  __builtin_amdgcn_global_load_lds((const __attribute__((address_space(1))) u32*)g,
                                   (__attribute__((address_space(3))) u32*)l, 16, 0, 0);
}

// ---------------- k_prep: wfrag + wih bf16 pack + batch bf16 pack + meta ----------------
__global__ void k_prep(const f32* __restrict__ w0f, const f32* __restrict__ w0b,
                       const f32* __restrict__ w1f, const f32* __restrict__ w1b,
                       const f32* __restrict__ wih0f, const f32* __restrict__ wih0b,
                       const f32* __restrict__ wih1f, const f32* __restrict__ wih1b,
                       const f32* __restrict__ batch, const int* __restrict__ lengths,
                       u16* __restrict__ wfrag, u16* __restrict__ wihbf,
                       u16* __restrict__ batchbf, int* __restrict__ meta){
  const int bx = blockIdx.x, tid = threadIdx.x;
  if (bx < 3072){
    int idx = bx*256 + tid;                 // < 786432
    int set = idx / 196608;
    int e   = idx % 196608;
    int w   = e / 24576;  int r  = e % 24576;
    int tau = r / 4096;   int r2 = r % 4096;
    int kc  = r2 >> 9;    int r3 = r2 & 511;
    int lane= r3 >> 3;    int j  = r3 & 7;
    int g = (tau>>1)*256 + w*32 + (tau&1)*16 + (lane & 15);
    int k = kc*32 + (lane>>4)*8 + j;
    const f32* src = (set==0)? w0f : (set==1)? w0b : (set==2)? w1f : w1b;
    float scale = (tau >= 4) ? S2F : S1F;
    wfrag[idx] = f2bf(src[g*256 + k] * scale);
  } else if (bx < 6912){
    int idx = (bx-3072)*256 + tid;          // < 983040
    if (idx < 196608){                      // layer0: [d][768][128] (wih stride 640, cols 0:128)
      int d = idx / 98304; int r = idx % 98304;
      int g = r >> 7, k = r & 127;
      wihbf[idx] = f2bf((d ? wih0b : wih0f)[g*640 + k]);
    } else {                                // layer1: [d][768][512]
      int i2 = idx - 196608;
      int d = i2 / 393216; int r = i2 % 393216;
      int g = r >> 9, k = r & 511;
      wihbf[idx] = f2bf((d ? wih1b : wih1f)[g*512 + k]);
    }
  } else if (bx < 15104){
    int idx = (bx-6912)*256 + tid;          // < 2097152
    batchbf[idx] = f2bf(batch[idx]);
  } else if (tid == 0){
    int Lmax = 0;
    for (int b=0;b<16;b++) Lmax = max(Lmax, lengths[b]);
    meta[0] = Lmax;
    int acc = 0;
    for (int b=0;b<16;b++){ meta[1+b] = acc; acc += lengths[b]; }
    meta[17] = acc;
    const int H2s[4] = {169,126,126,62};
    for (int br=0;br<4;br++)
      for (int b=0;b<16;b++){
        double ratio = (double)lengths[b] / (double)Lmax;
        meta[32 + br*16 + b] = (int)((double)H2s[br] * ratio);
      }
  }
}

// ---------------- conv1 all 4 branches (+BN8+ReLU+maxpool2) ----------------
__global__ void k_conv1a(const f32* __restrict__ x,
                         const f32* __restrict__ w0,const f32* __restrict__ w1,const f32* __restrict__ w2,const f32* __restrict__ w3,
                         const f32* __restrict__ cb0,const f32* __restrict__ cb1,const f32* __restrict__ cb2,const f32* __restrict__ cb3,
                         const f32* __restrict__ bg, const f32* __restrict__ bbp,
                         const f32* __restrict__ bm, const f32* __restrict__ bv,
                         f32* __restrict__ o0, f32* __restrict__ o1, f32* __restrict__ o2, f32* __restrict__ o3){
  const int br = blockIdx.z;
  const int Ks[4]={4,8,16,32}, Ss[4]={1,2,4,8}, Hps[4]={510,254,126,62}, Wps[4]={62,30,14,6};
  const int K = Ks[br], s = Ss[br], Hp = Hps[br], Wp = Wps[br];
  const f32* w  = (br==0)?w0:(br==1)?w1:(br==2)?w2:w3;
  const f32* cb = (br==0)?cb0:(br==1)?cb1:(br==2)?cb2:cb3;
  f32* out      = (br==0)?o0:(br==1)?o1:(br==2)?o2:o3;
  __shared__ f32 wl[8192];
  int b = blockIdx.y;
  int KK = K*K;
  for (int i=threadIdx.x; i<8*KK; i+=256) wl[i] = w[i];
  __syncthreads();
  int idx = blockIdx.x*256 + threadIdx.x;
  int npix = Hp*Wp;
  if (idx >= npix) return;
  int ph = idx / Wp, pw = idx % Wp;
  float mx[8];
  #pragma unroll
  for (int c=0;c<8;c++) mx[c] = -1e30f;
  for (int dy=0; dy<2; ++dy)
  for (int dx=0; dx<2; ++dx){
    const f32* xb = x + ((size_t)b*1024 + (size_t)(ph*2+dy)*s)*128 + (size_t)(pw*2+dx)*s;
    float acc[8];
    #pragma unroll
    for (int c=0;c<8;c++) acc[c] = 0.f;
    for (int kh=0; kh<K; ++kh){
      const f32* xr = xb + kh*128;
      for (int kw=0; kw<K; ++kw){
        float xv = xr[kw];
        #pragma unroll
        for (int c=0;c<8;c++) acc[c] = fmaf(xv, wl[c*KK + kh*K + kw], acc[c]);
      }
    }
    #pragma unroll
    for (int c=0;c<8;c++) mx[c] = fmaxf(mx[c], acc[c]);
  }
  #pragma unroll
  for (int c=0;c<8;c++){
    float scale = bg[c] * rsqrtf(bv[c] + 1e-5f);
    float val = (mx[c] + cb[c] - bm[c]) * scale + bbp[c];
    out[(((size_t)b*8 + c)*Hp + ph)*Wp + pw] = fmaxf(val, 0.f);
  }
}

// ---------------- conv2 all 4 branches (+BN3+ReLU) ----------------
__global__ void k_conv2a(const f32* __restrict__ i0,const f32* __restrict__ i1,const f32* __restrict__ i2,const f32* __restrict__ i3,
                         const f32* __restrict__ w0,const f32* __restrict__ w1,const f32* __restrict__ w2,const f32* __restrict__ w3,
                         const f32* __restrict__ cb0,const f32* __restrict__ cb1,const f32* __restrict__ cb2,const f32* __restrict__ cb3,
                         const f32* __restrict__ bg, const f32* __restrict__ bbp,
                         const f32* __restrict__ bm, const f32* __restrict__ bv,
                         f32* __restrict__ o0, f32* __restrict__ o1, f32* __restrict__ o2, f32* __restrict__ o3){
  const int br = blockIdx.z;
  const int Ks[4]={5,3,1,1}, Ss[4]={3,2,1,1}, Hins[4]={510,254,126,62}, Wins[4]={62,30,14,6};
  const int Hos[4]={169,126,126,62}, Wos[4]={20,14,14,6};
  const int K = Ks[br], s = Ss[br], Hin = Hins[br], Win = Wins[br], Ho = Hos[br], Wo = Wos[br];
  const f32* in = (br==0)?i0:(br==1)?i1:(br==2)?i2:i3;
  const f32* w  = (br==0)?w0:(br==1)?w1:(br==2)?w2:w3;
  const f32* cb = (br==0)?cb0:(br==1)?cb1:(br==2)?cb2:cb3;
  f32* out      = (br==0)?o0:(br==1)?o1:(br==2)?o2:o3;
  __shared__ f32 wl[600];
  int b = blockIdx.y;
  int KK = K*K, sz = 24*KK;
  for (int i=threadIdx.x; i<sz; i+=256) wl[i] = w[i];
  __syncthreads();
  int idx = blockIdx.x*256 + threadIdx.x;
  int npix = Ho*Wo;
  if (idx >= npix) return;
  int oh = idx / Wo, ow = idx % Wo;
  float acc[3] = {0.f,0.f,0.f};
  for (int ci=0; ci<8; ++ci){
    const f32* xp = in + (((size_t)b*8 + ci)*Hin + (size_t)oh*s)*Win + (size_t)ow*s;
    for (int kh=0; kh<K; ++kh)
      for (int kw=0; kw<K; ++kw){
        float xv = xp[kh*Win + kw];
        #pragma unroll
        for (int co=0; co<3; ++co) acc[co] = fmaf(xv, wl[(co*8+ci)*KK + kh*K + kw], acc[co]);
      }
  }
  #pragma unroll
  for (int co=0; co<3; ++co){
    float scale = bg[co] * rsqrtf(bv[co] + 1e-5f);
    float val = (acc[co] + cb[co] - bm[co]) * scale + bbp[co];
    out[(((size_t)b*3 + co)*Ho + oh)*Wo + ow] = fmaxf(val, 0.f);
  }
}

// ---------------- per-batch bilinear resize, all 4 branches ----------------
__global__ void k_resizea(const f32* __restrict__ s0,const f32* __restrict__ s1,const f32* __restrict__ s2,const f32* __restrict__ s3,
                          const int* __restrict__ meta, f32* __restrict__ feats){
  const int br = blockIdx.z;
  const int H2s[4]={169,126,126,62}, W2s[4]={20,14,14,6}, Hos[4]={90,67,67,33}, Wos[4]={9,6,6,2};
  const int offs[4]={0,2430,3636,4842};
  const int H2 = H2s[br], W2 = W2s[br], Ho = Hos[br], Wo = Wos[br], off = offs[br];
  const f32* src = (br==0)?s0:(br==1)?s1:(br==2)?s2:s3;
  int idx = blockIdx.x*256 + threadIdx.x;
  int per_b = 3*Ho*Wo;
  if (idx >= 16*per_b) return;
  int b = idx / per_b;  int r = idx % per_b;
  int c = r / (Ho*Wo);  int r2 = r % (Ho*Wo);
  int ho = r2 / Wo, wo = r2 % Wo;
  int hs = meta[32 + br*16 + b];
  float cy = ((float)ho + 0.5f) * ((float)hs / (float)Ho) - 0.5f;
  cy = fmaxf(cy, 0.f);
  int him = hs - 1;
  int i0 = min((int)floorf(cy), him);
  int i1 = min(i0 + 1, him);
  float w1 = fminf(fmaxf(cy - (float)i0, 0.f), 1.f);
  float rw = (float)((double)W2 / (double)Wo);
  float cw = ((float)wo + 0.5f) * rw - 0.5f;
  cw = fminf(fmaxf(cw, 0.f), (float)(W2 - 1));
  int j0 = (int)floorf(cw);
  int j1 = min(j0 + 1, W2 - 1);
  float ww = cw - (float)j0;
  const f32* sp = src + (size_t)(b*3 + c) * H2 * W2;
  float v00 = sp[i0*W2 + j0], v01 = sp[i0*W2 + j1];
  float v10 = sp[i1*W2 + j0], v11 = sp[i1*W2 + j1];
  float col0 = v00*(1.f - w1) + v10*w1;
  float col1 = v01*(1.f - w1) + v11*w1;
  feats[(size_t)b*5040 + off + (c*Ho + ho)*Wo + wo] = col0*(1.f - ww) + col1*ww;
}

// ---------------- fc1 ----------------
__global__ void k_fc1(const f32* __restrict__ feats, const f32* __restrict__ w,
                      const f32* __restrict__ bias, f32* __restrict__ rfeat){
  int b = blockIdx.x;
  int o0 = blockIdx.y * 64;
  int sub = threadIdx.x & 31, og = threadIdx.x >> 5;
  const f32* fp = feats + (size_t)b*5040;
  for (int oi = og; oi < 64; oi += 8){
    int o = o0 + oi;
    const f32* wp = w + (size_t)o*5040;
    float acc = 0.f;
    for (int k = sub; k < 5040; k += 32) acc = fmaf(fp[k], wp[k], acc);
    #pragma unroll
    for (int m=16; m; m>>=1) acc += __shfl_xor(acc, m, 32);
    if (sub == 0) rfeat[(size_t)b*512 + o] = acc + bias[o];
  }
}

// ---------------- ydc (vectorized f32x4) ----------------
__global__ void k_ydc(const f32* __restrict__ rfeat, const f32* __restrict__ wihf, const f32* __restrict__ wihb,
                      const f32* __restrict__ bihf, const f32* __restrict__ bihb, f32* __restrict__ ydc){
  int idx = blockIdx.x*256 + threadIdx.x;   // < 24576
  int d = idx / 12288;  int r = idx % 12288;
  int b = r / 768;      int g = r % 768;
  const f32* wih = d ? wihb : wihf;
  const f32* bih = d ? bihb : bihf;
  const f32x4* rp = (const f32x4*)(rfeat + (size_t)b*512);
  const f32x4* wp = (const f32x4*)(wih + (size_t)g*640 + 128);
  float acc = bih[g];
  for (int k=0;k<128;k++){
    f32x4 a = rp[k], w4 = wp[k];
    acc = fmaf(a[0],w4[0],acc); acc = fmaf(a[1],w4[1],acc);
    acc = fmaf(a[2],w4[2],acc); acc = fmaf(a[3],w4[3],acc);
  }
  ydc[idx] = acc;
}

// ---------------- xW GEMM: pre-packed bf16 + global_load_lds staging; OUTPUT bf16 ----------------
template<int LAYER>
__global__ __launch_bounds__(256)
void k_xw(const u16* __restrict__ Abf, const u16* __restrict__ wihbf,
          const f32* __restrict__ biasf, const f32* __restrict__ biasb,
          const f32* __restrict__ ydc, const f32* __restrict__ bhf, const f32* __restrict__ bhb,
          const int* __restrict__ lengths, u16* __restrict__ xwbuf){
  constexpr int KT = (LAYER==0) ? 128 : 512;
  const int dir = blockIdx.z;
  u16* out = xwbuf + (size_t)dir * 16384 * 768;
  const u16* wd = wihbf + (size_t)dir * 768 * KT;
  const int brow = blockIdx.x * 64, bcol = blockIdx.y * 64;
  __shared__ __attribute__((aligned(16))) u16 As[2048], Bs[2048];   // 64 x 32 bf16 each
  const int tid = threadIdx.x, lane = tid & 63, wid = tid >> 6;
  const int srow = wid*16 + (lane >> 2);
  const int cg   = (lane & 3) ^ (srow & 3);      // pre-swizzled global chunk
  int tt = (brow + srow) >> 4, bb = (brow + srow) & 15;
  int srct = tt;
  if (dir){ int L = lengths[bb]; srct = (tt < L) ? (L - 1 - tt) : tt; }
  const u16* asrc = Abf + ((size_t)bb*1024 + srct)*KT + cg*8;
  const u16* bsrc = wd + (size_t)(bcol + srow)*KT + cg*8;
  u16* adst = As + wid*512;    // wave-uniform LDS base
  u16* bdst = Bs + wid*512;
  const int l15 = lane & 15, grp = lane >> 4;
  const int arow_f = wid*16 + l15;
  const int aoff = arow_f*32 + ((grp ^ (arow_f & 3))*8);
  f32x4 acc[4];
  #pragma unroll
  for (int nt=0; nt<4; ++nt) acc[nt] = (f32x4){0.f,0.f,0.f,0.f};

  for (int kc=0; kc<KT/32; ++kc){
    gld16(asrc + kc*32, adst);
    gld16(bsrc + kc*32, bdst);
    __syncthreads();
    s16x8 a = *(const s16x8*)&As[aoff];
    #pragma unroll
    for (int nt=0; nt<4; ++nt){
      int cb = nt*16 + l15;
      s16x8 bfr = *(const s16x8*)&Bs[cb*32 + ((grp ^ (cb & 3))*8)];
      acc[nt] = __builtin_amdgcn_mfma_f32_16x16x32_bf16(a, bfr, acc[nt], 0, 0, 0);
    }
    __syncthreads();
  }
  const f32* bh = dir ? bhb : bhf;
  #pragma unroll
  for (int nt=0; nt<4; ++nt){
    int col = bcol + nt*16 + l15;
    float bhadd = (col < 512) ? bh[col] : 0.f;
    float scale = (col < 512) ? S1F : S2F;
    #pragma unroll
    for (int q=0; q<4; ++q){
      int row = brow + wid*16 + grp*4 + q;
      float bias;
      if (LAYER == 0) bias = ydc[((size_t)dir*16 + (row & 15))*768 + col];
      else            bias = (dir ? biasb : biasf)[col];
      out[(size_t)row*768 + col] = f2bf((acc[nt][q] + bias + bhadd) * scale);
    }
  }
}

// ---------------- GRU recurrence (round-7 structure; xw now bf16) ----------------
#define GRU_STEP(t_, u_, X_) do { \
  f32x4 a_r0={0.f,0.f,0.f,0.f}, a_r1={0.f,0.f,0.f,0.f}; \
  f32x4 a_z0={0.f,0.f,0.f,0.f}, a_z1={0.f,0.f,0.f,0.f}; \
  f32x4 a_n0={bhn0,bhn0,bhn0,bhn0}, a_n1={bhn1,bhn1,bhn1,bhn1}; \
  _Pragma("unroll") \
  for (int kc=0; kc<8; ++kc){ \
    s16x8 a = *(const s16x8*)&h_lds[(u_)*576 + hro + kc*32 + lq*8]; \
    a_r0 = __builtin_amdgcn_mfma_f32_16x16x32_bf16(a, wreg[0][kc], a_r0, 0,0,0); \
    a_r1 = __builtin_amdgcn_mfma_f32_16x16x32_bf16(a, wreg[1][kc], a_r1, 0,0,0); \
    a_z0 = __builtin_amdgcn_mfma_f32_16x16x32_bf16(a, wreg[2][kc], a_z0, 0,0,0); \
    a_z1 = __builtin_amdgcn_mfma_f32_16x16x32_bf16(a, wreg[3][kc], a_z1, 0,0,0); \
    a_n0 = __builtin_amdgcn_mfma_f32_16x16x32_bf16(a, wreg[4][kc], a_n0, 0,0,0); \
    a_n1 = __builtin_amdgcn_mfma_f32_16x16x32_bf16(a, wreg[5][kc], a_n1, 0,0,0); \
  } \
  { \
    float ar0 = qi ? a_r0[1] : a_r0[0], ar1 = qi ? a_r1[1] : a_r1[0]; \
    float az0 = qi ? a_z0[1] : a_z0[0], az1 = qi ? a_z1[1] : a_z1[0]; \
    float an0 = qi ? a_n0[1] : a_n0[0], an1 = qi ? a_n1[1] : a_n1[0]; \
    float ar = tpi ? ar1 : ar0; \
    float az = tpi ? az1 : az0; \
    float an = tpi ? an1 : an0; \
    float r = __builtin_amdgcn_rcpf(1.0f + __builtin_amdgcn_exp2f(X_[0] + ar)); \
    float z = __builtin_amdgcn_rcpf(1.0f + __builtin_amdgcn_exp2f(X_[1] + az)); \
    float n = fmaf(-2.0f, __builtin_amdgcn_rcpf(__builtin_amdgcn_exp2f(fmaf(r, an, X_[2])) + 1.0f), 1.0f); \
    float hv = fmaf(z, hp - n, n); \
    hp = hv; \
    u32 ub = __float_as_uint(hv); \
    u16 hb16 = (u16)((ub + 0x8000u)>>16); \
    h_lds[((u_)^1)*576 + qi*288 + jme] = hb16; \
    if (dir == 0){ *hb = hb16; hb += 512; } \
    else { int tpos = ((t_) < Lq) ? (Lq-1-(t_)) : (t_); hb[(size_t)tpos*512] = hb16; } \
  } \
  asm volatile("s_waitcnt lgkmcnt(0)\n\ts_barrier" ::: "memory"); \
} while(0)

template<int LAYER>
__global__ __launch_bounds__(512, 2)
void k_recur(const u16* __restrict__ xw, const u16* __restrict__ wfrag,
             const f32* __restrict__ bhhf, const f32* __restrict__ bhhb,
             const int* __restrict__ lengths, u16* __restrict__ hbf){
  __shared__ u16 h_lds[1152];     // 2 bufs x 2 rows x 288 u16
  const int dir = blockIdx.y;
  const int b0  = blockIdx.x * 2;
  const int tid = threadIdx.x, lane = tid & 63, wid = tid >> 6;
  const u16* xwd = xw + (size_t)dir * 12582912;
  const f32* bhh = dir ? bhhb : bhhf;
  const u16* wf = wfrag + (size_t)(LAYER*2 + dir) * 196608;

  s16x8 wreg[6][8];
  #pragma unroll
  for (int tau=0; tau<6; ++tau)
    #pragma unroll
    for (int kc=0; kc<8; ++kc)
      wreg[tau][kc] = *(const s16x8*)(wf + ((size_t)((wid*6+tau)*8 + kc)*64 + lane)*8);
  if (tid < 576) ((u32*)h_lds)[tid] = 0;

  const int l15 = lane & 15, lq = lane >> 4;
  const int jlo = (wid << 5) + l15;
  const int hro = (l15 & 1) * 288;
  const int qi  = lq & 1;
  const int tpi = lq >> 1;
  const int jme = jlo + tpi*16;
  const float bhn0 = bhh[512 + jlo] * S2F;
  const float bhn1 = bhh[512 + jlo + 16] * S2F;
  const int Lq = lengths[b0 + qi];
  float hp = 0.f;

  const u16* xp = xwd + (size_t)(b0+qi)*768 + jme;
  u16* hb = hbf + ((size_t)(b0+qi)*1024)*512 + dir*256 + jme;

  float X0[3], X1[3];
  X0[0]=B2F(xp[0]); X0[1]=B2F(xp[256]); X0[2]=B2F(xp[512]); xp += 12288;
  X1[0]=B2F(xp[0]); X1[1]=B2F(xp[256]); X1[2]=B2F(xp[512]); xp += 12288;
  __syncthreads();

  for (int t2=0; t2<1024; t2+=2){
    GRU_STEP(t2,   0, X0);
    X0[0]=B2F(xp[0]); X0[1]=B2F(xp[256]); X0[2]=B2F(xp[512]); xp += 12288;
    GRU_STEP(t2+1, 1, X1);
    X1[0]=B2F(xp[0]); X1[1]=B2F(xp[256]); X1[2]=B2F(xp[512]); xp += 12288;
  }
}

// ---------------- final FC + length gather (t-chunked, bf16 h) ----------------
__global__ void k_final(const u16* __restrict__ h1, const f32* __restrict__ fcw, const f32* __restrict__ fcb,
                        const int* __restrict__ lengths, const int* __restrict__ meta, f32* __restrict__ out){
  int b = blockIdx.y;
  int t0 = blockIdx.x * 16;
  int lane = threadIdx.x & 63, w = threadIdx.x >> 6;
  int L = lengths[b];
  if (t0 >= L) return;
  const f32* wp = fcw + (size_t)lane*512;
  float bias = (lane < 61) ? fcb[lane] : 0.f;
  int rowbase = meta[1 + b];
  #pragma unroll
  for (int p=0;p<4;p++){
    int t = t0 + p*4 + w;
    if (t < L && lane < 61){
      const u16* hp = h1 + ((size_t)b*1024 + t)*512;
      float acc = 0.f;
      for (int k8=0;k8<64;k8++){
        u32x4 hv = *(const u32x4*)(hp + k8*8);
        f32x4 w0 = *(const f32x4*)(wp + k8*8);
        f32x4 w1 = *(const f32x4*)(wp + k8*8 + 4);
        acc = fmaf(__uint_as_float(hv[0] << 16),        w0[0], acc);
        acc = fmaf(__uint_as_float(hv[0] & 0xffff0000u),w0[1], acc);
        acc = fmaf(__uint_as_float(hv[1] << 16),        w0[2], acc);
        acc = fmaf(__uint_as_float(hv[1] & 0xffff0000u),w0[3], acc);
        acc = fmaf(__uint_as_float(hv[2] << 16),        w1[0], acc);
        acc = fmaf(__uint_as_float(hv[2] & 0xffff0000u),w1[1], acc);
        acc = fmaf(__uint_as_float(hv[3] << 16),        w1[2], acc);
        acc = fmaf(__uint_as_float(hv[3] & 0xffff0000u),w1[3], acc);
      }
      out[(size_t)(rowbase + t)*61 + lane] = acc + bias;
    }
  }
}

// ---------------- host ----------------
extern "C" void kernel_launch(void* const* d_in, const int* in_sizes, int n_in,
                              void* d_out, int out_size, void* d_ws, size_t ws_size,
                              hipStream_t stream){
  const f32* batch = (const f32*)d_in[0];
  const f32* c1w[4] = {(const f32*)d_in[1],(const f32*)d_in[3],(const f32*)d_in[5],(const f32*)d_in[7]};
  const f32* c1b[4] = {(const f32*)d_in[2],(const f32*)d_in[4],(const f32*)d_in[6],(const f32*)d_in[8]};
  const f32* c2w[4] = {(const f32*)d_in[9],(const f32*)d_in[11],(const f32*)d_in[13],(const f32*)d_in[15]};
  const f32* c2b[4] = {(const f32*)d_in[10],(const f32*)d_in[12],(const f32*)d_in[14],(const f32*)d_in[16]};
  const f32 *bn8g=(const f32*)d_in[17], *bn8b=(const f32*)d_in[18], *bn8m=(const f32*)d_in[19], *bn8v=(const f32*)d_in[20];
  const f32 *bn3g=(const f32*)d_in[21], *bn3b=(const f32*)d_in[22], *bn3m=(const f32*)d_in[23], *bn3v=(const f32*)d_in[24];
  const f32 *fc1w=(const f32*)d_in[25], *fc1b=(const f32*)d_in[26];
  const f32 *g0f_wih=(const f32*)d_in[27], *g0f_whh=(const f32*)d_in[28], *g0f_bih=(const f32*)d_in[29], *g0f_bhh=(const f32*)d_in[30];
  const f32 *g0b_wih=(const f32*)d_in[31], *g0b_whh=(const f32*)d_in[32], *g0b_bih=(const f32*)d_in[33], *g0b_bhh=(const f32*)d_in[34];
  const f32 *g1f_wih=(const f32*)d_in[35], *g1f_whh=(const f32*)d_in[36], *g1f_bih=(const f32*)d_in[37], *g1f_bhh=(const f32*)d_in[38];
  const f32 *g1b_wih=(const f32*)d_in[39], *g1b_whh=(const f32*)d_in[40], *g1b_bih=(const f32*)d_in[41], *g1b_bhh=(const f32*)d_in[42];
  const f32 *fcw=(const f32*)d_in[43], *fcb=(const f32*)d_in[44];
  const int* lengths = (const int*)d_in[45];
  f32* out = (f32*)d_out;

  char* base = (char*)d_ws;
  size_t off = 0;
  auto alloc = [&](size_t bytes)->void*{
    void* p = base + off;
    off += bytes;
    off = (off + 255) & ~(size_t)255;
    return p;
  };

  static const int Hp[4]={510,254,126,62}, Wpp[4]={62,30,14,6};
  static const int Ho2[4]={169,126,126,62}, Wo2[4]={20,14,14,6};

  f32* r1[4]; for (int i=0;i<4;i++) r1[i] = (f32*)alloc((size_t)16*8*Hp[i]*Wpp[i]*4);
  f32* r2[4]; for (int i=0;i<4;i++) r2[i] = (f32*)alloc((size_t)16*3*Ho2[i]*Wo2[i]*4);
  f32* feats = (f32*)alloc((size_t)16*5040*4);
  f32* rfeat = (f32*)alloc((size_t)16*512*4);
  f32* ydc   = (f32*)alloc((size_t)2*16*768*4);
  int* meta  = (int*)alloc(128*4);
  u16* wfrag = (u16*)alloc((size_t)4*196608*2);
  u16* wihbf = (u16*)alloc((size_t)983040*2);          // [L0: 2x768x128][L1: 2x768x512]
  u16* batchbf=(u16*)alloc((size_t)16*1024*128*2);
  u16* xwb   = (u16*)alloc((size_t)2*1024*16*768*2);   // bf16 now (50MB)
  u16* hbf0  = (u16*)alloc((size_t)16*1024*512*2);
  u16* hbf1  = (u16*)alloc((size_t)16*1024*512*2);

  k_prep<<<15105,256,0,stream>>>(g0f_whh, g0b_whh, g1f_whh, g1b_whh,
                                 g0f_wih, g0b_wih, g1f_wih, g1b_wih,
                                 batch, lengths, wfrag, wihbf, batchbf, meta);
  k_conv1a<<<dim3(124,16,4),256,0,stream>>>(batch, c1w[0],c1w[1],c1w[2],c1w[3],
                                            c1b[0],c1b[1],c1b[2],c1b[3],
                                            bn8g,bn8b,bn8m,bn8v, r1[0],r1[1],r1[2],r1[3]);
  k_conv2a<<<dim3(14,16,4),256,0,stream>>>(r1[0],r1[1],r1[2],r1[3],
                                           c2w[0],c2w[1],c2w[2],c2w[3],
                                           c2b[0],c2b[1],c2b[2],c2b[3],
                                           bn3g,bn3b,bn3m,bn3v, r2[0],r2[1],r2[2],r2[3]);
  k_resizea<<<dim3(152,1,4),256,0,stream>>>(r2[0],r2[1],r2[2],r2[3], meta, feats);
  k_fc1<<<dim3(16,8),256,0,stream>>>(feats, fc1w, fc1b, rfeat);
  k_ydc<<<96,256,0,stream>>>(rfeat, g0f_wih, g0b_wih, g0f_bih, g0b_bih, ydc);
  k_xw<0><<<dim3(256,12,2),256,0,stream>>>(batchbf, wihbf, nullptr, nullptr,
                                           ydc, g0f_bhh, g0b_bhh, lengths, xwb);
  k_recur<0><<<dim3(8,2),512,0,stream>>>(xwb, wfrag, g0f_bhh, g0b_bhh, lengths, hbf0);
  k_xw<1><<<dim3(256,12,2),256,0,stream>>>(hbf0, wihbf + 196608, g1f_bih, g1b_bih,
                                           nullptr, g1f_bhh, g1b_bhh, lengths, xwb);
  k_recur<1><<<dim3(8,2),512,0,stream>>>(xwb, wfrag, g1f_bhh, g1b_bhh, lengths, hbf1);
  k_final<<<dim3(64,16),256,0,stream>>>(hbf1, fcw, fcb, lengths, meta, out);
}

// Round 10
// 2925.023 us; speedup vs baseline: 1.0188x; 1.0188x over previous
//
#include <hip/hip_runtime.h>

typedef float f32;
typedef unsigned int u32;
typedef unsigned short u16;
typedef short s16x8 __attribute__((ext_vector_type(8)));
typedef float f32x4 __attribute__((ext_vector_type(4)));
typedef u32 u32x4 __attribute__((ext_vector_type(4)));

#define S1F (-1.4426950408889634f)   /* -log2(e): r,z pre-scale */
#define S2F ( 2.8853900817779268f)   /* 2*log2(e): n pre-scale  */

__device__ __forceinline__ u16 f2bf(float x){
  u32 u = __float_as_uint(x);
  u32 r = u + 0x7FFFu + ((u >> 16) & 1u);   // round-to-nearest-even
  return (u16)(r >> 16);
}

// async global->LDS 16B/lane (dest = wave-uniform base + lane*16)
__device__ __forceinline__ void gld16(const u16* g, u16* l){
  __builtin_amdgcn_global_load_lds((const __attribute__((address_space(1))) u32*)g,
                                   (__attribute__((address_space(3))) u32*)l, 16, 0, 0);
}

// ---------------- k_prep: wfrag + wih bf16 pack + batch bf16 pack + meta ----------------
__global__ void k_prep(const f32* __restrict__ w0f, const f32* __restrict__ w0b,
                       const f32* __restrict__ w1f, const f32* __restrict__ w1b,
                       const f32* __restrict__ wih0f, const f32* __restrict__ wih0b,
                       const f32* __restrict__ wih1f, const f32* __restrict__ wih1b,
                       const f32* __restrict__ batch, const int* __restrict__ lengths,
                       u16* __restrict__ wfrag, u16* __restrict__ wihbf,
                       u16* __restrict__ batchbf, int* __restrict__ meta){
  const int bx = blockIdx.x, tid = threadIdx.x;
  if (bx < 3072){
    int idx = bx*256 + tid;                 // < 786432
    int set = idx / 196608;
    int e   = idx % 196608;
    int w   = e / 24576;  int r  = e % 24576;
    int tau = r / 4096;   int r2 = r % 4096;
    int kc  = r2 >> 9;    int r3 = r2 & 511;
    int lane= r3 >> 3;    int j  = r3 & 7;
    int g = (tau>>1)*256 + w*32 + (tau&1)*16 + (lane & 15);
    int k = kc*32 + (lane>>4)*8 + j;
    const f32* src = (set==0)? w0f : (set==1)? w0b : (set==2)? w1f : w1b;
    float scale = (tau >= 4) ? S2F : S1F;
    wfrag[idx] = f2bf(src[g*256 + k] * scale);
  } else if (bx < 6912){
    int idx = (bx-3072)*256 + tid;          // < 983040
    if (idx < 196608){                      // layer0: [d][768][128] (wih stride 640, cols 0:128)
      int d = idx / 98304; int r = idx % 98304;
      int g = r >> 7, k = r & 127;
      wihbf[idx] = f2bf((d ? wih0b : wih0f)[g*640 + k]);
    } else {                                // layer1: [d][768][512]
      int i2 = idx - 196608;
      int d = i2 / 393216; int r = i2 % 393216;
      int g = r >> 9, k = r & 511;
      wihbf[idx] = f2bf((d ? wih1b : wih1f)[g*512 + k]);
    }
  } else if (bx < 15104){
    int idx = (bx-6912)*256 + tid;          // < 2097152
    batchbf[idx] = f2bf(batch[idx]);
  } else if (tid == 0){
    int Lmax = 0;
    for (int b=0;b<16;b++) Lmax = max(Lmax, lengths[b]);
    meta[0] = Lmax;
    int acc = 0;
    for (int b=0;b<16;b++){ meta[1+b] = acc; acc += lengths[b]; }
    meta[17] = acc;
    const int H2s[4] = {169,126,126,62};
    for (int br=0;br<4;br++)
      for (int b=0;b<16;b++){
        double ratio = (double)lengths[b] / (double)Lmax;
        meta[32 + br*16 + b] = (int)((double)H2s[br] * ratio);
      }
  }
}

// ---------------- conv1 all 4 branches (+BN8+ReLU+maxpool2) ----------------
__global__ void k_conv1a(const f32* __restrict__ x,
                         const f32* __restrict__ w0,const f32* __restrict__ w1,const f32* __restrict__ w2,const f32* __restrict__ w3,
                         const f32* __restrict__ cb0,const f32* __restrict__ cb1,const f32* __restrict__ cb2,const f32* __restrict__ cb3,
                         const f32* __restrict__ bg, const f32* __restrict__ bbp,
                         const f32* __restrict__ bm, const f32* __restrict__ bv,
                         f32* __restrict__ o0, f32* __restrict__ o1, f32* __restrict__ o2, f32* __restrict__ o3){
  const int br = blockIdx.z;
  const int Ks[4]={4,8,16,32}, Ss[4]={1,2,4,8}, Hps[4]={510,254,126,62}, Wps[4]={62,30,14,6};
  const int K = Ks[br], s = Ss[br], Hp = Hps[br], Wp = Wps[br];
  const f32* w  = (br==0)?w0:(br==1)?w1:(br==2)?w2:w3;
  const f32* cb = (br==0)?cb0:(br==1)?cb1:(br==2)?cb2:cb3;
  f32* out      = (br==0)?o0:(br==1)?o1:(br==2)?o2:o3;
  __shared__ f32 wl[8192];
  int b = blockIdx.y;
  int KK = K*K;
  for (int i=threadIdx.x; i<8*KK; i+=256) wl[i] = w[i];
  __syncthreads();
  int idx = blockIdx.x*256 + threadIdx.x;
  int npix = Hp*Wp;
  if (idx >= npix) return;
  int ph = idx / Wp, pw = idx % Wp;
  float mx[8];
  #pragma unroll
  for (int c=0;c<8;c++) mx[c] = -1e30f;
  for (int dy=0; dy<2; ++dy)
  for (int dx=0; dx<2; ++dx){
    const f32* xb = x + ((size_t)b*1024 + (size_t)(ph*2+dy)*s)*128 + (size_t)(pw*2+dx)*s;
    float acc[8];
    #pragma unroll
    for (int c=0;c<8;c++) acc[c] = 0.f;
    for (int kh=0; kh<K; ++kh){
      const f32* xr = xb + kh*128;
      for (int kw=0; kw<K; ++kw){
        float xv = xr[kw];
        #pragma unroll
        for (int c=0;c<8;c++) acc[c] = fmaf(xv, wl[c*KK + kh*K + kw], acc[c]);
      }
    }
    #pragma unroll
    for (int c=0;c<8;c++) mx[c] = fmaxf(mx[c], acc[c]);
  }
  #pragma unroll
  for (int c=0;c<8;c++){
    float scale = bg[c] * rsqrtf(bv[c] + 1e-5f);
    float val = (mx[c] + cb[c] - bm[c]) * scale + bbp[c];
    out[(((size_t)b*8 + c)*Hp + ph)*Wp + pw] = fmaxf(val, 0.f);
  }
}

// ---------------- conv2 all 4 branches (+BN3+ReLU) ----------------
__global__ void k_conv2a(const f32* __restrict__ i0,const f32* __restrict__ i1,const f32* __restrict__ i2,const f32* __restrict__ i3,
                         const f32* __restrict__ w0,const f32* __restrict__ w1,const f32* __restrict__ w2,const f32* __restrict__ w3,
                         const f32* __restrict__ cb0,const f32* __restrict__ cb1,const f32* __restrict__ cb2,const f32* __restrict__ cb3,
                         const f32* __restrict__ bg, const f32* __restrict__ bbp,
                         const f32* __restrict__ bm, const f32* __restrict__ bv,
                         f32* __restrict__ o0, f32* __restrict__ o1, f32* __restrict__ o2, f32* __restrict__ o3){
  const int br = blockIdx.z;
  const int Ks[4]={5,3,1,1}, Ss[4]={3,2,1,1}, Hins[4]={510,254,126,62}, Wins[4]={62,30,14,6};
  const int Hos[4]={169,126,126,62}, Wos[4]={20,14,14,6};
  const int K = Ks[br], s = Ss[br], Hin = Hins[br], Win = Wins[br], Ho = Hos[br], Wo = Wos[br];
  const f32* in = (br==0)?i0:(br==1)?i1:(br==2)?i2:i3;
  const f32* w  = (br==0)?w0:(br==1)?w1:(br==2)?w2:w3;
  const f32* cb = (br==0)?cb0:(br==1)?cb1:(br==2)?cb2:cb3;
  f32* out      = (br==0)?o0:(br==1)?o1:(br==2)?o2:o3;
  __shared__ f32 wl[600];
  int b = blockIdx.y;
  int KK = K*K, sz = 24*KK;
  for (int i=threadIdx.x; i<sz; i+=256) wl[i] = w[i];
  __syncthreads();
  int idx = blockIdx.x*256 + threadIdx.x;
  int npix = Ho*Wo;
  if (idx >= npix) return;
  int oh = idx / Wo, ow = idx % Wo;
  float acc[3] = {0.f,0.f,0.f};
  for (int ci=0; ci<8; ++ci){
    const f32* xp = in + (((size_t)b*8 + ci)*Hin + (size_t)oh*s)*Win + (size_t)ow*s;
    for (int kh=0; kh<K; ++kh)
      for (int kw=0; kw<K; ++kw){
        float xv = xp[kh*Win + kw];
        #pragma unroll
        for (int co=0; co<3; ++co) acc[co] = fmaf(xv, wl[(co*8+ci)*KK + kh*K + kw], acc[co]);
      }
  }
  #pragma unroll
  for (int co=0; co<3; ++co){
    float scale = bg[co] * rsqrtf(bv[co] + 1e-5f);
    float val = (acc[co] + cb[co] - bm[co]) * scale + bbp[co];
    out[(((size_t)b*3 + co)*Ho + oh)*Wo + ow] = fmaxf(val, 0.f);
  }
}

// ---------------- per-batch bilinear resize, all 4 branches ----------------
__global__ void k_resizea(const f32* __restrict__ s0,const f32* __restrict__ s1,const f32* __restrict__ s2,const f32* __restrict__ s3,
                          const int* __restrict__ meta, f32* __restrict__ feats){
  const int br = blockIdx.z;
  const int H2s[4]={169,126,126,62}, W2s[4]={20,14,14,6}, Hos[4]={90,67,67,33}, Wos[4]={9,6,6,2};
  const int offs[4]={0,2430,3636,4842};
  const int H2 = H2s[br], W2 = W2s[br], Ho = Hos[br], Wo = Wos[br], off = offs[br];
  const f32* src = (br==0)?s0:(br==1)?s1:(br==2)?s2:s3;
  int idx = blockIdx.x*256 + threadIdx.x;
  int per_b = 3*Ho*Wo;
  if (idx >= 16*per_b) return;
  int b = idx / per_b;  int r = idx % per_b;
  int c = r / (Ho*Wo);  int r2 = r % (Ho*Wo);
  int ho = r2 / Wo, wo = r2 % Wo;
  int hs = meta[32 + br*16 + b];
  float cy = ((float)ho + 0.5f) * ((float)hs / (float)Ho) - 0.5f;
  cy = fmaxf(cy, 0.f);
  int him = hs - 1;
  int i0 = min((int)floorf(cy), him);
  int i1 = min(i0 + 1, him);
  float w1 = fminf(fmaxf(cy - (float)i0, 0.f), 1.f);
  float rw = (float)((double)W2 / (double)Wo);
  float cw = ((float)wo + 0.5f) * rw - 0.5f;
  cw = fminf(fmaxf(cw, 0.f), (float)(W2 - 1));
  int j0 = (int)floorf(cw);
  int j1 = min(j0 + 1, W2 - 1);
  float ww = cw - (float)j0;
  const f32* sp = src + (size_t)(b*3 + c) * H2 * W2;
  float v00 = sp[i0*W2 + j0], v01 = sp[i0*W2 + j1];
  float v10 = sp[i1*W2 + j0], v11 = sp[i1*W2 + j1];
  float col0 = v00*(1.f - w1) + v10*w1;
  float col1 = v01*(1.f - w1) + v11*w1;
  feats[(size_t)b*5040 + off + (c*Ho + ho)*Wo + wo] = col0*(1.f - ww) + col1*ww;
}

// ---------------- fc1 ----------------
__global__ void k_fc1(const f32* __restrict__ feats, const f32* __restrict__ w,
                      const f32* __restrict__ bias, f32* __restrict__ rfeat){
  int b = blockIdx.x;
  int o0 = blockIdx.y * 64;
  int sub = threadIdx.x & 31, og = threadIdx.x >> 5;
  const f32* fp = feats + (size_t)b*5040;
  for (int oi = og; oi < 64; oi += 8){
    int o = o0 + oi;
    const f32* wp = w + (size_t)o*5040;
    float acc = 0.f;
    for (int k = sub; k < 5040; k += 32) acc = fmaf(fp[k], wp[k], acc);
    #pragma unroll
    for (int m=16; m; m>>=1) acc += __shfl_xor(acc, m, 32);
    if (sub == 0) rfeat[(size_t)b*512 + o] = acc + bias[o];
  }
}

// ---------------- ydc (vectorized f32x4) ----------------
__global__ void k_ydc(const f32* __restrict__ rfeat, const f32* __restrict__ wihf, const f32* __restrict__ wihb,
                      const f32* __restrict__ bihf, const f32* __restrict__ bihb, f32* __restrict__ ydc){
  int idx = blockIdx.x*256 + threadIdx.x;   // < 24576
  int d = idx / 12288;  int r = idx % 12288;
  int b = r / 768;      int g = r % 768;
  const f32* wih = d ? wihb : wihf;
  const f32* bih = d ? bihb : bihf;
  const f32x4* rp = (const f32x4*)(rfeat + (size_t)b*512);
  const f32x4* wp = (const f32x4*)(wih + (size_t)g*640 + 128);
  float acc = bih[g];
  for (int k=0;k<128;k++){
    f32x4 a = rp[k], w4 = wp[k];
    acc = fmaf(a[0],w4[0],acc); acc = fmaf(a[1],w4[1],acc);
    acc = fmaf(a[2],w4[2],acc); acc = fmaf(a[3],w4[3],acc);
  }
  ydc[idx] = acc;
}

// ---------------- xW GEMM: pre-packed bf16 + global_load_lds staging; OUTPUT f32 ----------------
template<int LAYER>
__global__ __launch_bounds__(256)
void k_xw(const u16* __restrict__ Abf, const u16* __restrict__ wihbf,
          const f32* __restrict__ biasf, const f32* __restrict__ biasb,
          const f32* __restrict__ ydc, const f32* __restrict__ bhf, const f32* __restrict__ bhb,
          const int* __restrict__ lengths, f32* __restrict__ xwbuf){
  constexpr int KT = (LAYER==0) ? 128 : 512;
  const int dir = blockIdx.z;
  f32* out = xwbuf + (size_t)dir * 16384 * 768;
  const u16* wd = wihbf + (size_t)dir * 768 * KT;
  const int brow = blockIdx.x * 64, bcol = blockIdx.y * 64;
  __shared__ __attribute__((aligned(16))) u16 As[2048], Bs[2048];   // 64 x 32 bf16 each
  const int tid = threadIdx.x, lane = tid & 63, wid = tid >> 6;
  const int srow = wid*16 + (lane >> 2);
  const int cg   = (lane & 3) ^ (srow & 3);      // pre-swizzled global chunk
  int tt = (brow + srow) >> 4, bb = (brow + srow) & 15;
  int srct = tt;
  if (dir){ int L = lengths[bb]; srct = (tt < L) ? (L - 1 - tt) : tt; }
  const u16* asrc = Abf + ((size_t)bb*1024 + srct)*KT + cg*8;
  const u16* bsrc = wd + (size_t)(bcol + srow)*KT + cg*8;
  u16* adst = As + wid*512;    // wave-uniform LDS base
  u16* bdst = Bs + wid*512;
  const int l15 = lane & 15, grp = lane >> 4;
  const int arow_f = wid*16 + l15;
  const int aoff = arow_f*32 + ((grp ^ (arow_f & 3))*8);
  f32x4 acc[4];
  #pragma unroll
  for (int nt=0; nt<4; ++nt) acc[nt] = (f32x4){0.f,0.f,0.f,0.f};

  for (int kc=0; kc<KT/32; ++kc){
    gld16(asrc + kc*32, adst);
    gld16(bsrc + kc*32, bdst);
    __syncthreads();
    s16x8 a = *(const s16x8*)&As[aoff];
    #pragma unroll
    for (int nt=0; nt<4; ++nt){
      int cb = nt*16 + l15;
      s16x8 bfr = *(const s16x8*)&Bs[cb*32 + ((grp ^ (cb & 3))*8)];
      acc[nt] = __builtin_amdgcn_mfma_f32_16x16x32_bf16(a, bfr, acc[nt], 0, 0, 0);
    }
    __syncthreads();
  }
  const f32* bh = dir ? bhb : bhf;
  #pragma unroll
  for (int nt=0; nt<4; ++nt){
    int col = bcol + nt*16 + l15;
    float bhadd = (col < 512) ? bh[col] : 0.f;
    float scale = (col < 512) ? S1F : S2F;
    #pragma unroll
    for (int q=0; q<4; ++q){
      int row = brow + wid*16 + grp*4 + q;
      float bias;
      if (LAYER == 0) bias = ydc[((size_t)dir*16 + (row & 15))*768 + col];
      else            bias = (dir ? biasb : biasf)[col];
      out[(size_t)row*768 + col] = (acc[nt][q] + bias + bhadd) * scale;
    }
  }
}

// ---------------- GRU recurrence (round-7 structure; h stored as bf16) ----------------
#define GRU_STEP(t_, u_, X_) do { \
  f32x4 a_r0={0.f,0.f,0.f,0.f}, a_r1={0.f,0.f,0.f,0.f}; \
  f32x4 a_z0={0.f,0.f,0.f,0.f}, a_z1={0.f,0.f,0.f,0.f}; \
  f32x4 a_n0={bhn0,bhn0,bhn0,bhn0}, a_n1={bhn1,bhn1,bhn1,bhn1}; \
  _Pragma("unroll") \
  for (int kc=0; kc<8; ++kc){ \
    s16x8 a = *(const s16x8*)&h_lds[(u_)*576 + hro + kc*32 + lq*8]; \
    a_r0 = __builtin_amdgcn_mfma_f32_16x16x32_bf16(a, wreg[0][kc], a_r0, 0,0,0); \
    a_r1 = __builtin_amdgcn_mfma_f32_16x16x32_bf16(a, wreg[1][kc], a_r1, 0,0,0); \
    a_z0 = __builtin_amdgcn_mfma_f32_16x16x32_bf16(a, wreg[2][kc], a_z0, 0,0,0); \
    a_z1 = __builtin_amdgcn_mfma_f32_16x16x32_bf16(a, wreg[3][kc], a_z1, 0,0,0); \
    a_n0 = __builtin_amdgcn_mfma_f32_16x16x32_bf16(a, wreg[4][kc], a_n0, 0,0,0); \
    a_n1 = __builtin_amdgcn_mfma_f32_16x16x32_bf16(a, wreg[5][kc], a_n1, 0,0,0); \
  } \
  { \
    float ar0 = qi ? a_r0[1] : a_r0[0], ar1 = qi ? a_r1[1] : a_r1[0]; \
    float az0 = qi ? a_z0[1] : a_z0[0], az1 = qi ? a_z1[1] : a_z1[0]; \
    float an0 = qi ? a_n0[1] : a_n0[0], an1 = qi ? a_n1[1] : a_n1[0]; \
    float ar = tpi ? ar1 : ar0; \
    float az = tpi ? az1 : az0; \
    float an = tpi ? an1 : an0; \
    float r = __builtin_amdgcn_rcpf(1.0f + __builtin_amdgcn_exp2f(X_[0] + ar)); \
    float z = __builtin_amdgcn_rcpf(1.0f + __builtin_amdgcn_exp2f(X_[1] + az)); \
    float n = fmaf(-2.0f, __builtin_amdgcn_rcpf(__builtin_amdgcn_exp2f(fmaf(r, an, X_[2])) + 1.0f), 1.0f); \
    float hv = fmaf(z, hp - n, n); \
    hp = hv; \
    u32 ub = __float_as_uint(hv); \
    u16 hb16 = (u16)((ub + 0x8000u)>>16); \
    h_lds[((u_)^1)*576 + qi*288 + jme] = hb16; \
    if (dir == 0){ *hb = hb16; hb += 512; } \
    else { int tpos = ((t_) < Lq) ? (Lq-1-(t_)) : (t_); hb[(size_t)tpos*512] = hb16; } \
  } \
  asm volatile("s_waitcnt lgkmcnt(0)\n\ts_barrier" ::: "memory"); \
} while(0)

template<int LAYER>
__global__ __launch_bounds__(512, 2)
void k_recur(const f32* __restrict__ xw, const u16* __restrict__ wfrag,
             const f32* __restrict__ bhhf, const f32* __restrict__ bhhb,
             const int* __restrict__ lengths, u16* __restrict__ hbf){
  __shared__ u16 h_lds[1152];     // 2 bufs x 2 rows x 288 u16
  const int dir = blockIdx.y;
  const int b0  = blockIdx.x * 2;
  const int tid = threadIdx.x, lane = tid & 63, wid = tid >> 6;
  const f32* xwd = xw + (size_t)dir * 12582912;
  const f32* bhh = dir ? bhhb : bhhf;
  const u16* wf = wfrag + (size_t)(LAYER*2 + dir) * 196608;

  s16x8 wreg[6][8];
  #pragma unroll
  for (int tau=0; tau<6; ++tau)
    #pragma unroll
    for (int kc=0; kc<8; ++kc)
      wreg[tau][kc] = *(const s16x8*)(wf + ((size_t)((wid*6+tau)*8 + kc)*64 + lane)*8);
  if (tid < 576) ((u32*)h_lds)[tid] = 0;

  const int l15 = lane & 15, lq = lane >> 4;
  const int jlo = (wid << 5) + l15;
  const int hro = (l15 & 1) * 288;
  const int qi  = lq & 1;
  const int tpi = lq >> 1;
  const int jme = jlo + tpi*16;
  const float bhn0 = bhh[512 + jlo] * S2F;
  const float bhn1 = bhh[512 + jlo + 16] * S2F;
  const int Lq = lengths[b0 + qi];
  float hp = 0.f;

  const f32* xp = xwd + (size_t)(b0+qi)*768 + jme;
  u16* hb = hbf + ((size_t)(b0+qi)*1024)*512 + dir*256 + jme;

  float X0[3], X1[3];
  X0[0]=xp[0]; X0[1]=xp[256]; X0[2]=xp[512]; xp += 12288;
  X1[0]=xp[0]; X1[1]=xp[256]; X1[2]=xp[512]; xp += 12288;
  __syncthreads();

  for (int t2=0; t2<1024; t2+=2){
    GRU_STEP(t2,   0, X0);
    X0[0]=xp[0]; X0[1]=xp[256]; X0[2]=xp[512]; xp += 12288;
    GRU_STEP(t2+1, 1, X1);
    X1[0]=xp[0]; X1[1]=xp[256]; X1[2]=xp[512]; xp += 12288;
  }
}

// ---------------- final FC + length gather (t-chunked, bf16 h) ----------------
__global__ void k_final(const u16* __restrict__ h1, const f32* __restrict__ fcw, const f32* __restrict__ fcb,
                        const int* __restrict__ lengths, const int* __restrict__ meta, f32* __restrict__ out){
  int b = blockIdx.y;
  int t0 = blockIdx.x * 16;
  int lane = threadIdx.x & 63, w = threadIdx.x >> 6;
  int L = lengths[b];
  if (t0 >= L) return;
  const f32* wp = fcw + (size_t)lane*512;
  float bias = (lane < 61) ? fcb[lane] : 0.f;
  int rowbase = meta[1 + b];
  #pragma unroll
  for (int p=0;p<4;p++){
    int t = t0 + p*4 + w;
    if (t < L && lane < 61){
      const u16* hp = h1 + ((size_t)b*1024 + t)*512;
      float acc = 0.f;
      for (int k8=0;k8<64;k8++){
        u32x4 hv = *(const u32x4*)(hp + k8*8);
        f32x4 w0 = *(const f32x4*)(wp + k8*8);
        f32x4 w1 = *(const f32x4*)(wp + k8*8 + 4);
        acc = fmaf(__uint_as_float(hv[0] << 16),        w0[0], acc);
        acc = fmaf(__uint_as_float(hv[0] & 0xffff0000u),w0[1], acc);
        acc = fmaf(__uint_as_float(hv[1] << 16),        w0[2], acc);
        acc = fmaf(__uint_as_float(hv[1] & 0xffff0000u),w0[3], acc);
        acc = fmaf(__uint_as_float(hv[2] << 16),        w1[0], acc);
        acc = fmaf(__uint_as_float(hv[2] & 0xffff0000u),w1[1], acc);
        acc = fmaf(__uint_as_float(hv[3] << 16),        w1[2], acc);
        acc = fmaf(__uint_as_float(hv[3] & 0xffff0000u),w1[3], acc);
      }
      out[(size_t)(rowbase + t)*61 + lane] = acc + bias;
    }
  }
}

// ---------------- host ----------------
extern "C" void kernel_launch(void* const* d_in, const int* in_sizes, int n_in,
                              void* d_out, int out_size, void* d_ws, size_t ws_size,
                              hipStream_t stream){
  const f32* batch = (const f32*)d_in[0];
  const f32* c1w[4] = {(const f32*)d_in[1],(const f32*)d_in[3],(const f32*)d_in[5],(const f32*)d_in[7]};
  const f32* c1b[4] = {(const f32*)d_in[2],(const f32*)d_in[4],(const f32*)d_in[6],(const f32*)d_in[8]};
  const f32* c2w[4] = {(const f32*)d_in[9],(const f32*)d_in[11],(const f32*)d_in[13],(const f32*)d_in[15]};
  const f32* c2b[4] = {(const f32*)d_in[10],(const f32*)d_in[12],(const f32*)d_in[14],(const f32*)d_in[16]};
  const f32 *bn8g=(const f32*)d_in[17], *bn8b=(const f32*)d_in[18], *bn8m=(const f32*)d_in[19], *bn8v=(const f32*)d_in[20];
  const f32 *bn3g=(const f32*)d_in[21], *bn3b=(const f32*)d_in[22], *bn3m=(const f32*)d_in[23], *bn3v=(const f32*)d_in[24];
  const f32 *fc1w=(const f32*)d_in[25], *fc1b=(const f32*)d_in[26];
  const f32 *g0f_wih=(const f32*)d_in[27], *g0f_whh=(const f32*)d_in[28], *g0f_bih=(const f32*)d_in[29], *g0f_bhh=(const f32*)d_in[30];
  const f32 *g0b_wih=(const f32*)d_in[31], *g0b_whh=(const f32*)d_in[32], *g0b_bih=(const f32*)d_in[33], *g0b_bhh=(const f32*)d_in[34];
  const f32 *g1f_wih=(const f32*)d_in[35], *g1f_whh=(const f32*)d_in[36], *g1f_bih=(const f32*)d_in[37], *g1f_bhh=(const f32*)d_in[38];
  const f32 *g1b_wih=(const f32*)d_in[39], *g1b_whh=(const f32*)d_in[40], *g1b_bih=(const f32*)d_in[41], *g1b_bhh=(const f32*)d_in[42];
  const f32 *fcw=(const f32*)d_in[43], *fcb=(const f32*)d_in[44];
  const int* lengths = (const int*)d_in[45];
  f32* out = (f32*)d_out;

  char* base = (char*)d_ws;
  size_t off = 0;
  auto alloc = [&](size_t bytes)->void*{
    void* p = base + off;
    off += bytes;
    off = (off + 255) & ~(size_t)255;
    return p;
  };

  static const int Hp[4]={510,254,126,62}, Wpp[4]={62,30,14,6};
  static const int Ho2[4]={169,126,126,62}, Wo2[4]={20,14,14,6};

  f32* r1[4]; for (int i=0;i<4;i++) r1[i] = (f32*)alloc((size_t)16*8*Hp[i]*Wpp[i]*4);
  f32* r2[4]; for (int i=0;i<4;i++) r2[i] = (f32*)alloc((size_t)16*3*Ho2[i]*Wo2[i]*4);
  f32* feats = (f32*)alloc((size_t)16*5040*4);
  f32* rfeat = (f32*)alloc((size_t)16*512*4);
  f32* ydc   = (f32*)alloc((size_t)2*16*768*4);
  int* meta  = (int*)alloc(128*4);
  u16* wfrag = (u16*)alloc((size_t)4*196608*2);
  u16* wihbf = (u16*)alloc((size_t)983040*2);          // [L0: 2x768x128][L1: 2x768x512]
  u16* batchbf=(u16*)alloc((size_t)16*1024*128*2);
  f32* xwb   = (f32*)alloc((size_t)2*1024*16*768*4);   // f32 (round-8 best config)
  u16* hbf0  = (u16*)alloc((size_t)16*1024*512*2);
  u16* hbf1  = (u16*)alloc((size_t)16*1024*512*2);

  k_prep<<<15105,256,0,stream>>>(g0f_whh, g0b_whh, g1f_whh, g1b_whh,
                                 g0f_wih, g0b_wih, g1f_wih, g1b_wih,
                                 batch, lengths, wfrag, wihbf, batchbf, meta);
  k_conv1a<<<dim3(124,16,4),256,0,stream>>>(batch, c1w[0],c1w[1],c1w[2],c1w[3],
                                            c1b[0],c1b[1],c1b[2],c1b[3],
                                            bn8g,bn8b,bn8m,bn8v, r1[0],r1[1],r1[2],r1[3]);
  k_conv2a<<<dim3(14,16,4),256,0,stream>>>(r1[0],r1[1],r1[2],r1[3],
                                           c2w[0],c2w[1],c2w[2],c2w[3],
                                           c2b[0],c2b[1],c2b[2],c2b[3],
                                           bn3g,bn3b,bn3m,bn3v, r2[0],r2[1],r2[2],r2[3]);
  k_resizea<<<dim3(152,1,4),256,0,stream>>>(r2[0],r2[1],r2[2],r2[3], meta, feats);
  k_fc1<<<dim3(16,8),256,0,stream>>>(feats, fc1w, fc1b, rfeat);
  k_ydc<<<96,256,0,stream>>>(rfeat, g0f_wih, g0b_wih, g0f_bih, g0b_bih, ydc);
  k_xw<0><<<dim3(256,12,2),256,0,stream>>>(batchbf, wihbf, nullptr, nullptr,
                                           ydc, g0f_bhh, g0b_bhh, lengths, xwb);
  k_recur<0><<<dim3(8,2),512,0,stream>>>(xwb, wfrag, g0f_bhh, g0b_bhh, lengths, hbf0);
  k_xw<1><<<dim3(256,12,2),256,0,stream>>>(hbf0, wihbf + 196608, g1f_bih, g1b_bih,
                                           nullptr, g1f_bhh, g1b_bhh, lengths, xwb);
  k_recur<1><<<dim3(8,2),512,0,stream>>>(xwb, wfrag, g1f_bhh, g1b_bhh, lengths, hbf1);
  k_final<<<dim3(64,16),256,0,stream>>>(hbf1, fcw, fcb, lengths, meta, out);
}